// Round 1
// baseline (205.100 us; speedup 1.0000x reference)
//
#include <hip/hip_runtime.h>
#include <stdint.h>

#define N_OUT 100000
#define CIN 16
#define COUT 32
#define VPB 16           // voxels per block
#define ACC_STRIDE 1028  // 1024 + 4 dword pad (bank spread for MFMA A-reads)
#define ECH 14           // edge chunk size

typedef __attribute__((ext_vector_type(4))) float f32x4;
typedef __attribute__((ext_vector_type(8))) __bf16 bf16x8;

__device__ __forceinline__ float clampf(float x, float lo, float hi) {
  return fminf(fmaxf(x, lo), hi);
}

// prep: kernel fp32 [64 taps][16 cin][32 cout] -> bf16 MFMA B-fragment table
// idx = ((kchunk*2 + ntile)*64 + lane)*8 + j
//   k = kchunk*32 + (lane>>4)*8 + j   (k = tap*16 + c, K = 1024)
//   o = ntile*16 + (lane&15)
__global__ void prep_kernel(const float* __restrict__ kern, __bf16* __restrict__ wsB) {
  int t = blockIdx.x * blockDim.x + threadIdx.x;  // 0..32767
  int j = t & 7;
  int lane = (t >> 3) & 63;
  int ntile = (t >> 9) & 1;
  int kchunk = t >> 10;
  int k = kchunk * 32 + (lane >> 4) * 8 + j;
  int o = ntile * 16 + (lane & 15);
  wsB[t] = (__bf16)kern[k * COUT + o];
}

__global__ __launch_bounds__(256, 2) void cconv_kernel(
    const float* __restrict__ feats, const float* __restrict__ inp_pts,
    const float* __restrict__ out_pts, const float* __restrict__ out_ext,
    const float* __restrict__ scale, const float* __restrict__ ndist,
    const int* __restrict__ nidx, const int* __restrict__ rsp,
    const float* __restrict__ bias, const __bf16* __restrict__ wsB,
    float* __restrict__ out) {
  __shared__ float acc[VPB * ACC_STRIDE];   // 65792 B
  __shared__ float recs[VPB][ECH][8];       // 7168 B
  __shared__ float red[2 * 64 * 4];         // 2048 B
  __shared__ float denS[VPB];
  __shared__ int cmaxS;

  int tid = threadIdx.x;
  int vbase = blockIdx.x * VPB;
  if (tid == 0) cmaxS = 0;
  if (tid < VPB) denS[tid] = 0.f;
  for (int i = tid; i < VPB * ACC_STRIDE / 4; i += 256)
    ((f32x4*)acc)[i] = (f32x4){0.f, 0.f, 0.f, 0.f};

  int v = tid >> 4, lane16 = tid & 15;
  int n = vbase + v;
  int rs0 = rsp[n];
  int cnt = rsp[n + 1] - rs0;
  __syncthreads();
  if (lane16 == 0) atomicMax(&cmaxS, cnt);
  __syncthreads();
  int cmax = cmaxS;

  // scatter roles: 8 corners x 2 channel-halves
  int corner = lane16 & 7, cg = lane16 >> 3;
  int ca = corner >> 2, cb = (corner >> 1) & 1, cc = corner & 1;

  for (int chunk = 0; chunk < cmax; chunk += ECH) {
    int m_v = cnt - chunk;
    if (m_v > ECH) m_v = ECH;
    // phase 1a: one lane per edge -> geometry record
    if (lane16 < m_v) {
      int e = rs0 + chunk + lane16;
      int nbr = nidx[e];
      float dsq = ndist[e];
      float p6 = 1.f - dsq;
      p6 = p6 * p6 * p6;
      p6 = clampf(p6, 0.f, 1.f);
      float imp = scale[e] * p6;
      float inv = 2.f / out_ext[n];
      float rx = (inp_pts[nbr * 3 + 0] - out_pts[n * 3 + 0]) * inv;
      float ry = (inp_pts[nbr * 3 + 1] - out_pts[n * 3 + 1]) * inv;
      float rz = (inp_pts[nbr * 3 + 2] - out_pts[n * 3 + 2]) * inv;
      float l2 = sqrtf(rx * rx + ry * ry + rz * rz);
      float linf = fmaxf(fabsf(rx), fmaxf(fabsf(ry), fabsf(rz)));
      float s = (linf > 0.f) ? (l2 / fmaxf(linf, 1e-12f)) : 0.f;
      float qx = clampf(rx * s, -1.f, 1.f);
      float qy = clampf(ry * s, -1.f, 1.f);
      float qz = clampf(rz * s, -1.f, 1.f);
      float tx = (qx + 1.f) * 1.5f, ty = (qy + 1.f) * 1.5f, tz = (qz + 1.f) * 1.5f;
      float fx0 = clampf(floorf(tx), 0.f, 2.f);
      float fy0 = clampf(floorf(ty), 0.f, 2.f);
      float fz0 = clampf(floorf(tz), 0.f, 2.f);
      int ix = (int)fx0, iy = (int)fy0, iz = (int)fz0;
      float fx = tx - fx0, fy = ty - fy0, fz = tz - fz0;
      int cbase = ix * 16 + iy * 4 + iz;
      float* rp = recs[v][lane16];
      rp[0] = fx; rp[1] = fy; rp[2] = fz; rp[3] = imp;
      rp[4] = __int_as_float(nbr);
      rp[5] = __int_as_float(cbase);
      atomicAdd(&denS[v], imp);
    }
    __syncthreads();
    // phase 1b: scatter into dense acc (each lane owns distinct (corner, half))
    for (int e2 = 0; e2 < m_v; ++e2) {
      const float* rp = recs[v][e2];
      float fx = rp[0], fy = rp[1], fz = rp[2], imp = rp[3];
      int nbr = __float_as_int(rp[4]);
      int cbase = __float_as_int(rp[5]);
      float w = (ca ? fx : 1.f - fx) * (cb ? fy : 1.f - fy) *
                (cc ? fz : 1.f - fz) * imp;
      int tap = cbase + ca * 16 + cb * 4 + cc;
      const f32x4* fp = (const f32x4*)(feats + nbr * CIN + cg * 8);
      f32x4 f0 = fp[0], f1 = fp[1];
      float* d = &acc[v * ACC_STRIDE + tap * 16 + cg * 8];
      f32x4 x0 = *(f32x4*)d;
      f32x4 x1 = *(f32x4*)(d + 4);
      x0 += w * f0;
      x1 += w * f1;
      *(f32x4*)d = x0;
      *(f32x4*)(d + 4) = x1;
    }
    __syncthreads();
  }

  // phase 2: [16 voxels x 1024] x [1024 x 32] via bf16 MFMA
  // wave w: ntile = w&1 (16 outputs), khalf = w>>1 (512 of K)
  int wid = tid >> 6, lane = tid & 63;
  int ntile = wid & 1, khalf = wid >> 1;
  int vrow = lane & 15, q = lane >> 4;
  f32x4 D = {0.f, 0.f, 0.f, 0.f};
  for (int kc = 0; kc < 16; ++kc) {
    int kchunk = khalf * 16 + kc;
    int kpos = kchunk * 32 + q * 8;
    const f32x4* ap = (const f32x4*)&acc[vrow * ACC_STRIDE + kpos];
    f32x4 a0 = ap[0], a1 = ap[1];
    bf16x8 af;
    af[0] = (__bf16)a0[0]; af[1] = (__bf16)a0[1];
    af[2] = (__bf16)a0[2]; af[3] = (__bf16)a0[3];
    af[4] = (__bf16)a1[0]; af[5] = (__bf16)a1[1];
    af[6] = (__bf16)a1[2]; af[7] = (__bf16)a1[3];
    bf16x8 bfrag = *(const bf16x8*)(wsB + ((kchunk * 2 + ntile) * 64 + lane) * 8);
    D = __builtin_amdgcn_mfma_f32_16x16x32_bf16(af, bfrag, D, 0, 0, 0);
  }
  if (khalf == 1) *(f32x4*)&red[(ntile * 64 + lane) * 4] = D;
  __syncthreads();
  if (khalf == 0) {
    f32x4 R = *(f32x4*)&red[(ntile * 64 + lane) * 4];
    D += R;
    int ocol = ntile * 16 + (lane & 15);
    float b = bias[ocol];
#pragma unroll
    for (int r = 0; r < 4; ++r) {
      int vv = q * 4 + r;  // D row = voxel
      float den = denS[vv];
      den = (den != 0.f) ? den : 1.f;
      float y = D[r] / den + b;
      out[(size_t)(vbase + vv) * COUT + ocol] = fmaxf(y, 0.f);
    }
  }
}

extern "C" void kernel_launch(void* const* d_in, const int* in_sizes, int n_in,
                              void* d_out, int out_size, void* d_ws, size_t ws_size,
                              hipStream_t stream) {
  const float* feats = (const float*)d_in[0];
  const float* inp_pts = (const float*)d_in[1];
  const float* out_pts = (const float*)d_in[2];
  const float* out_ext = (const float*)d_in[3];
  const float* scale = (const float*)d_in[4];
  const float* ndist = (const float*)d_in[5];
  const int* nidx = (const int*)d_in[6];
  const int* rsp = (const int*)d_in[7];
  const float* kern = (const float*)d_in[8];
  const float* bias = (const float*)d_in[9];
  __bf16* wsB = (__bf16*)d_ws;

  prep_kernel<<<128, 256, 0, stream>>>(kern, wsB);
  cconv_kernel<<<N_OUT / VPB, 256, 0, stream>>>(
      feats, inp_pts, out_pts, out_ext, scale, ndist, nidx, rsp, bias, wsB,
      (float*)d_out);
}